// Round 7
// baseline (7664.401 us; speedup 1.0000x reference)
//
#include <hip/hip_runtime.h>

// GRU, B=64, N=1024, T=512.
// Phase 1 (parallel): transpose x, weights -> bf16 [n][k], precompute
//   P2[t][s][j][b] = (x_t @ {W1z,W1r,W2} + bias) in bf16.
// Phase 2: ONE persistent kernel. ROUND-5 PROVEN PROTOCOL (flags +
//   drain + agent/LLC scope, 2.94 ms), restructured for LATENCY HIDING:
//   64 blocks (not 256); each block owns one 16-column j-slice and serves
//   ALL 4 batch-groups round-robin: phases (t,0),(t,1),(t,2),(t,3),(t+1,0)...
//   A group's publish->detect latency (~1.5us) is hidden behind ~3 phases
//   of the other groups' compute. 1-deep h prefetch: during phase p, check
//   phase p+1's flags ONCE (no spin); if set, issue its h loads now. Cold
//   path (flags not yet set) = round-5's spin+load, unchanged.
//   Weights are group-independent -> shared registers across phases.
//   hc[g] / red[g&1] statically indexed via #pragma unroll on g.
//   Correctness: per-group protocol byte-equivalent to round 5. Reader at
//   (t,g) needs publishes from phase (t-1,g) -- 4 phases earlier (acyclic,
//   no deadlock). Ring slot (t+1)&3 rewritten at (t,g) only after flags>=t
//   observed => all blocks passed (t-1,g) => their (t-3,g) reads retired.
//   t=0 reads skipped entirely (h_0=0 in registers). All spins bounded.

#define BATCH 64
#define NN 1024
#define TSTEPS 512
#define HB_ELEMS ((size_t)BATCH * NN)          // 65536 shorts per ring slot
#define SPIN_CAP 16384                          // legit waits ~us; cap ~ms

typedef __attribute__((ext_vector_type(8))) short short8;
typedef __attribute__((ext_vector_type(8))) unsigned short u16x8;
typedef __attribute__((ext_vector_type(4))) unsigned short u16x4;
typedef __attribute__((ext_vector_type(4))) float f32x4;

#define MFMA16(a, b, c) __builtin_amdgcn_mfma_f32_16x16x32_bf16((a), (b), (c), 0, 0, 0)

__device__ __forceinline__ unsigned short f2bf(float x) {
  union { float f; unsigned u; } v; v.f = x;
  unsigned u = v.u + 0x7FFFu + ((v.u >> 16) & 1u);   // round-to-nearest-even
  return (unsigned short)(u >> 16);
}
__device__ __forceinline__ float bf2f(unsigned short h) {
  union { unsigned u; float f; } v; v.u = ((unsigned)h) << 16; return v.f;
}

// ---- transpose flow_x [64][1024][512] fp32 -> xT [(t*64+b)][k] bf16 ----
__global__ void trans_x(const float* __restrict__ fx, unsigned short* __restrict__ xT) {
  int bid = blockIdx.x;
  int b   = bid >> 7;
  int rem = bid & 127;
  int kt  = rem >> 3;
  int tt  = rem & 7;
  __shared__ float tl[64][65];
  int tx = threadIdx.x & 63;
  int ty = threadIdx.x >> 6;
  const float* src = fx + ((size_t)(b * NN + kt * 64)) * TSTEPS + tt * 64;
#pragma unroll
  for (int i = 0; i < 16; i++) {
    int kr = i * 4 + ty;
    tl[kr][tx] = src[(size_t)kr * TSTEPS + tx];
  }
  __syncthreads();
#pragma unroll
  for (int i = 0; i < 16; i++) {
    int tr = i * 4 + ty;
    xT[((size_t)((tt * 64 + tr) * 64 + b)) * NN + kt * 64 + tx] = f2bf(tl[tx][tr]);
  }
}

// ---- weights fp32 -> wt bf16 [3*1024 rows n=(s,j)][1024 k] ----
__global__ void prep_w(const float* __restrict__ W1, const float* __restrict__ W2,
                       unsigned short* __restrict__ wt) {
  int bid = blockIdx.x;
  int s    = bid >> 8;
  int tile = bid & 255;
  int kt = tile >> 4, jt = tile & 15;
  const float* src = (s < 2) ? W1 : W2;
  int ld = (s < 2) ? 2048 : 1024;
  int co = (s == 1) ? 1024 : 0;
  __shared__ float tl[64][65];
  int tx = threadIdx.x & 63, ty = threadIdx.x >> 6;
#pragma unroll
  for (int i = 0; i < 16; i++) {
    int kr = i * 4 + ty;
    tl[kr][tx] = src[(size_t)(kt * 64 + kr) * ld + co + jt * 64 + tx];
  }
  __syncthreads();
#pragma unroll
  for (int i = 0; i < 16; i++) {
    int jr = i * 4 + ty;
    wt[((size_t)(s * NN + jt * 64 + jr)) * NN + kt * 64 + tx] = f2bf(tl[tx][jr]);
  }
}

// ---- P2[t][s][j][b] = x @ [W1 | W2] + bias, bf16 ----
__global__ __launch_bounds__(256) void precompute(
    const unsigned short* __restrict__ xT, const unsigned short* __restrict__ wt,
    const float* __restrict__ b1, const float* __restrict__ b2,
    unsigned short* __restrict__ P2) {
  int m0 = (blockIdx.x / 24) * 128;
  int n0 = (blockIdx.x % 24) * 128;
  __shared__ unsigned short As[128 * 40];
  __shared__ unsigned short Bs[128 * 40];
  int tid = threadIdx.x;
  int wave = tid >> 6, lane = tid & 63, q = lane >> 4, li = lane & 15;
  int wm = wave >> 1, wn = wave & 1;
  f32x4 acc[4][4];
#pragma unroll
  for (int a = 0; a < 4; a++)
#pragma unroll
    for (int b = 0; b < 4; b++) acc[a][b] = (f32x4)(0.f);

  for (int kk = 0; kk < 32; ++kk) {
    int K0 = kk * 32;
#pragma unroll
    for (int e = 0; e < 2; e++) {
      int c = tid * 2 + e;
      int row = c >> 2, part = c & 3;
      *(u16x8*)&As[row * 40 + part * 8] =
          *(const u16x8*)&xT[(size_t)(m0 + row) * NN + K0 + part * 8];
      *(u16x8*)&Bs[row * 40 + part * 8] =
          *(const u16x8*)&wt[(size_t)(n0 + row) * NN + K0 + part * 8];
    }
    __syncthreads();
    short8 af[4], bfr[4];
#pragma unroll
    for (int mt = 0; mt < 4; mt++)
      af[mt] = *(const short8*)&As[(wm * 64 + mt * 16 + li) * 40 + q * 8];
#pragma unroll
    for (int nt = 0; nt < 4; nt++)
      bfr[nt] = *(const short8*)&Bs[(wn * 64 + nt * 16 + li) * 40 + q * 8];
#pragma unroll
    for (int mt = 0; mt < 4; mt++)
#pragma unroll
      for (int nt = 0; nt < 4; nt++)
        acc[mt][nt] = MFMA16(af[mt], bfr[nt], acc[mt][nt]);
    __syncthreads();
  }
#pragma unroll
  for (int mt = 0; mt < 4; mt++) {
    int m = m0 + wm * 64 + mt * 16 + q * 4;
    int t = m >> 6, b = m & 63;
#pragma unroll
    for (int nt = 0; nt < 4; nt++) {
      int n = n0 + wn * 64 + nt * 16 + li;
      float bias = (n < 2048) ? b1[n] : b2[n - 2048];
      int s = n >> 10, j = n & 1023;
      f32x4 a = acc[mt][nt];
      u16x4 pk;
      pk.x = f2bf(a.x + bias); pk.y = f2bf(a.y + bias);
      pk.z = f2bf(a.z + bias); pk.w = f2bf(a.w + bias);
      *(u16x4*)&P2[(((size_t)t * 3 + s) * NN + j) * 64 + b] = pk;
    }
  }
}

#define AL(p)    __hip_atomic_load((p),  __ATOMIC_RELAXED, __HIP_MEMORY_SCOPE_AGENT)
#define AS(p, v) __hip_atomic_store((p), (v), __ATOMIC_RELAXED, __HIP_MEMORY_SCOPE_AGENT)

// ---- persistent scan: 64 blocks x 4 interleaved groups ----
// flags[(g*4+w)*64 + i] = publish count of producer jt=16w+i for group g.
// h ring: 4 slots of [64 b][1024 j] bf16 (rows partitioned by group).
__global__ __launch_bounds__(256, 1) void gru_scan(
    unsigned short* __restrict__ hb, const unsigned short* __restrict__ wt,
    const unsigned short* __restrict__ P2,
    const float* __restrict__ b1, const float* __restrict__ b2,
    float* __restrict__ out, unsigned* __restrict__ flags) {
  int jt = blockIdx.x;               // 0..63: j-slice
  int j0 = jt * 16;
  int tid = threadIdx.x, wave = tid >> 6, lane = tid & 63, q = lane >> 4, li = lane & 15;
  int kb = wave * 256;               // this wave's K-quarter

  const short8* Bz = (const short8*)&wt[((size_t)(0 * NN + j0 + li)) * NN + kb + q * 8];
  const short8* Br = (const short8*)&wt[((size_t)(1 * NN + j0 + li)) * NN + kb + q * 8];
  const short8* Bv = (const short8*)&wt[((size_t)(2 * NN + j0 + li)) * NN + kb + q * 8];
  short8 wz[8], wr[8], wv[8];
#pragma unroll
  for (int r = 0; r < 8; r++) {
    wz[r] = Bz[r * 4];
    wr[r] = Br[r * 4];
    wv[r] = Bv[r * 4];
  }

  int j = j0 + li;
  float b1z = b1[j], b1r = b1[NN + j], b2v = b2[j];
  const unsigned short* pzb = &P2[((size_t)0 * NN + j) * 64 + q * 4];
  const unsigned short* prb = &P2[((size_t)1 * NN + j) * 64 + q * 4];
  const unsigned short* pvb = &P2[((size_t)2 * NN + j) * 64 + q * 4];
  const size_t pstride = (size_t)3 * NN * 64;

  // A-fragment offset within a slot (u64 units), minus the group term:
  // full = g*4096 + li*256 + wave*64 + q*2   (row=g*16+li, 256 u64/row)
  const size_t abase = (size_t)li * 256 + (size_t)wave * 64 + q * 2;

  f32x4 hc[4];
#pragma unroll
  for (int g = 0; g < 4; g++) hc[g] = (f32x4)(0.f);
  __shared__ f32x4 red[2][9][64];

  short8 fa[8];
#pragma unroll
  for (int r = 0; r < 8; r++) fa[r] = (short8)0;   // h_0 = 0
  int fa_ok = 1;

  for (int t = 0; t < TSTEPS; t++) {
#pragma unroll
    for (int g = 0; g < 4; g++) {            // g compile-time (rule #20)
      u16x4 pz4, pr4, pv4;
      if (wave == 0) {                       // P2 stream, issue first
        size_t po = (size_t)t * pstride + g * 16;
        pz4 = *(const u16x4*)(pzb + po);
        pr4 = *(const u16x4*)(prb + po);
        pv4 = *(const u16x4*)(pvb + po);
      }
      if (!fa_ok) {                          // cold path: round-5 spin+load
        const unsigned* pollp = &flags[(unsigned)(g * 4 + wave) * 64 + li];
        unsigned tgt = (unsigned)t;
        int spins = 0;
        while (!__all((int)(AL(pollp) >= tgt))) {
          if (++spins > SPIN_CAP) break;     // hang-proof escape
          __builtin_amdgcn_s_sleep(1);
        }
        const unsigned long long* hin =
            (const unsigned long long*)(hb + ((size_t)(t & 3)) * HB_ELEMS) +
            (size_t)g * 4096 + abase;
        union { unsigned long long u[2]; short8 s; } u_;
#pragma unroll
        for (int r = 0; r < 8; r++) {
          u_.u[0] = AL(hin + r * 8);
          u_.u[1] = AL(hin + r * 8 + 1);
          fa[r] = u_.s;
        }
      }
      f32x4 az = (f32x4)(0.f), ar = (f32x4)(0.f), av = (f32x4)(0.f);
#pragma unroll
      for (int r = 0; r < 8; r++) {
        az = MFMA16(fa[r], wz[r], az);
        ar = MFMA16(fa[r], wr[r], ar);
        av = MFMA16(fa[r], wv[r], av);
      }
      // ---- prefetch next phase's A-fragments (single flag check) ----
      {
        int gn = (g + 1) & 3;
        int tn = (g == 3) ? t + 1 : t;
        fa_ok = 0;
        if (tn < TSTEPS) {
          if (tn == 0) {                     // t=0 phases: fa stays zeros
            fa_ok = 1;
          } else {
            const unsigned* pollp = &flags[(unsigned)(gn * 4 + wave) * 64 + li];
            unsigned f = AL(pollp);
            if (__all((int)(f >= (unsigned)tn))) {
              const unsigned long long* hin =
                  (const unsigned long long*)(hb + ((size_t)(tn & 3)) * HB_ELEMS) +
                  (size_t)gn * 4096 + abase;
              union { unsigned long long u[2]; short8 s; } u_;
#pragma unroll
              for (int r = 0; r < 8; r++) {
                u_.u[0] = AL(hin + r * 8);
                u_.u[1] = AL(hin + r * 8 + 1);
                fa[r] = u_.s;
              }
              fa_ok = 1;
            }
          }
        }
      }
      // cross-wave K reduction, buffer parity = g&1 (phases alternate)
      f32x4* rp = &red[g & 1][0][0];
      if (wave > 0) {
        rp[((wave - 1) * 3 + 0) * 64 + lane] = az;
        rp[((wave - 1) * 3 + 1) * 64 + lane] = ar;
        rp[((wave - 1) * 3 + 2) * 64 + lane] = av;
      }
      __syncthreads();
      if (wave == 0) {
#pragma unroll
        for (int w = 0; w < 3; w++) {
          az += rp[(w * 3 + 0) * 64 + lane];
          ar += rp[(w * 3 + 1) * 64 + lane];
          av += rp[(w * 3 + 2) * 64 + lane];
        }
#pragma unroll
        for (int reg = 0; reg < 4; reg++) {
          float z = 1.f / (1.f + __expf(-(az[reg] + bf2f(pz4[reg]) + b1z)));
          float r = 1.f / (1.f + __expf(-(ar[reg] + bf2f(pr4[reg]) + b1r)));
          float x = bf2f(pv4[reg]) + r * (av[reg] + b2v);
          float e = __expf(-2.f * fabsf(x));        // overflow-safe tanh
          float th = (1.f - e) / (1.f + e);
          float hh = (x >= 0.f) ? th : -th;
          hc[g][reg] = z * hc[g][reg] + (1.f - z) * hh;
        }
        if (t < TSTEPS - 1) {
          // publish h_{t+1}(group g) into slot (t+1)&3; drain; flag.
          unsigned* hout = (unsigned*)(hb + ((size_t)((t + 1) & 3)) * HB_ELEMS);
          int bbase = g * 16 + q * 4;
#pragma unroll
          for (int reg = 0; reg < 4; reg++) {
            unsigned mine = f2bf(hc[g][reg]);
            unsigned other = (unsigned)__shfl_xor((int)mine, 1, 64);
            if ((lane & 1) == 0) {
              unsigned packed = mine | (other << 16);
              AS(&hout[(size_t)(bbase + reg) * (NN / 2) + (j >> 1)], packed);
            }
          }
          asm volatile("s_waitcnt vmcnt(0)" ::: "memory");  // stores LLC-visible
          if (lane == 0)
            AS(&flags[(unsigned)(g * 4 + (jt >> 4)) * 64 + (jt & 15)],
               (unsigned)(t + 1));
        }
      }
    }
  }

  if (wave == 0) {   // out[b*N + j] straight from registers
#pragma unroll
    for (int g = 0; g < 4; g++)
#pragma unroll
      for (int reg = 0; reg < 4; reg++)
        out[(size_t)(g * 16 + q * 4 + reg) * NN + j] = hc[g][reg];
  }
}

extern "C" void kernel_launch(void* const* d_in, const int* in_sizes, int n_in,
                              void* d_out, int out_size, void* d_ws, size_t ws_size,
                              hipStream_t stream) {
  const float* flow_x = (const float*)d_in[0];
  const float* W1 = (const float*)d_in[1];
  const float* b1 = (const float*)d_in[2];
  const float* W2 = (const float*)d_in[3];
  const float* b2 = (const float*)d_in[4];
  float* out = (float*)d_out;
  char* ws = (char*)d_ws;
  size_t off = 0;
  auto take = [&](size_t bytes) -> char* {
    char* p = ws + off;
    off += (bytes + 255) & ~(size_t)255;
    return p;
  };
  unsigned short* wt    = (unsigned short*)take((size_t)3 * 1024 * 1024 * 2);
  unsigned short* xT    = (unsigned short*)take((size_t)32768 * 1024 * 2);
  unsigned short* P2    = (unsigned short*)take((size_t)512 * 3 * 1024 * 64 * 2);
  unsigned short* hb    = (unsigned short*)take((size_t)4 * HB_ELEMS * 2);
  unsigned*       flags = (unsigned*)take((size_t)16 * 64 * 4);

  if (off > ws_size) {
    hipMemsetAsync(d_out, 0, (size_t)out_size * 4, stream);
    return;
  }

  hipMemsetAsync(hb, 0, HB_ELEMS * 2, stream);          // slot 0 (belt+braces)
  hipMemsetAsync(flags, 0, (size_t)16 * 64 * 4, stream);

  prep_w<<<768, 256, 0, stream>>>(W1, W2, wt);
  trans_x<<<8192, 256, 0, stream>>>(flow_x, xT);
  precompute<<<6144, 256, 0, stream>>>(xT, wt, b1, b2, P2);

  void* args[] = {&hb, &wt, &P2, &b1, &b2, &out, &flags};
  hipLaunchCooperativeKernel((const void*)gru_scan, dim3(64), dim3(256),
                             args, 0, stream);
}

// Round 9
// 3030.905 us; speedup vs baseline: 2.5288x; 2.5288x over previous
//
#include <hip/hip_runtime.h>

// GRU, B=64, N=1024, T=512.
// Phase 1 (parallel): transpose x, weights -> bf16 [n][k], precompute
//   P2[t][s][j][b] = (x_t @ {W1z,W1r,W2} + bias) in bf16.
// Phase 2: ONE persistent kernel, 256 blocks x 256 thr = 4 INDEPENDENT
//   64-block scans (per 16-batch group mq). ROUND-5 PROVEN KERNEL
//   (2.94 ms scan) with two surgical micro-changes only:
//   (1) h A-fragment loads are 8x global_load_dwordx4 sc1 (agent/LLC
//       coherent, 16B) instead of 16x 8B atomic loads -- halves the
//       per-step LLC transaction burst (64 blk x 256 lanes x 16 loads
//       per group fired in a tight window each step).
//   (2) flag poll busy-spins 64 iterations before s_sleep(1) backoff.
//   Everything else byte-identical to round 5: per-writer monotone flag
//   words (no RMW), vmcnt(0) drain before flag store, agent-scope (LLC)
//   everywhere, 4-slot h ring with arrival-implies-retirement, LDS
//   reduction double-buffered by step parity, bounded spins (hang-proof).
//   Restructures (XCD-local r1-4, tagged-data r6, interleave r7, 32-col
//   blocks r8) all failed or regressed -- this topology is the keeper.

#define BATCH 64
#define NN 1024
#define TSTEPS 512
#define HB_ELEMS ((size_t)BATCH * NN)          // 65536 shorts per ring slot
#define SPIN_CAP 16384                          // legit waits ~us; cap ~ms

typedef __attribute__((ext_vector_type(8))) short short8;
typedef __attribute__((ext_vector_type(8))) unsigned short u16x8;
typedef __attribute__((ext_vector_type(4))) unsigned short u16x4;
typedef __attribute__((ext_vector_type(4))) float f32x4;

#define MFMA16(a, b, c) __builtin_amdgcn_mfma_f32_16x16x32_bf16((a), (b), (c), 0, 0, 0)

__device__ __forceinline__ unsigned short f2bf(float x) {
  union { float f; unsigned u; } v; v.f = x;
  unsigned u = v.u + 0x7FFFu + ((v.u >> 16) & 1u);   // round-to-nearest-even
  return (unsigned short)(u >> 16);
}
__device__ __forceinline__ float bf2f(unsigned short h) {
  union { unsigned u; float f; } v; v.u = ((unsigned)h) << 16; return v.f;
}

// ---- transpose flow_x [64][1024][512] fp32 -> xT [(t*64+b)][k] bf16 ----
__global__ void trans_x(const float* __restrict__ fx, unsigned short* __restrict__ xT) {
  int bid = blockIdx.x;
  int b   = bid >> 7;
  int rem = bid & 127;
  int kt  = rem >> 3;
  int tt  = rem & 7;
  __shared__ float tl[64][65];
  int tx = threadIdx.x & 63;
  int ty = threadIdx.x >> 6;
  const float* src = fx + ((size_t)(b * NN + kt * 64)) * TSTEPS + tt * 64;
#pragma unroll
  for (int i = 0; i < 16; i++) {
    int kr = i * 4 + ty;
    tl[kr][tx] = src[(size_t)kr * TSTEPS + tx];
  }
  __syncthreads();
#pragma unroll
  for (int i = 0; i < 16; i++) {
    int tr = i * 4 + ty;
    xT[((size_t)((tt * 64 + tr) * 64 + b)) * NN + kt * 64 + tx] = f2bf(tl[tx][tr]);
  }
}

// ---- weights fp32 -> wt bf16 [3*1024 rows n=(s,j)][1024 k] ----
__global__ void prep_w(const float* __restrict__ W1, const float* __restrict__ W2,
                       unsigned short* __restrict__ wt) {
  int bid = blockIdx.x;
  int s    = bid >> 8;
  int tile = bid & 255;
  int kt = tile >> 4, jt = tile & 15;
  const float* src = (s < 2) ? W1 : W2;
  int ld = (s < 2) ? 2048 : 1024;
  int co = (s == 1) ? 1024 : 0;
  __shared__ float tl[64][65];
  int tx = threadIdx.x & 63, ty = threadIdx.x >> 6;
#pragma unroll
  for (int i = 0; i < 16; i++) {
    int kr = i * 4 + ty;
    tl[kr][tx] = src[(size_t)(kt * 64 + kr) * ld + co + jt * 64 + tx];
  }
  __syncthreads();
#pragma unroll
  for (int i = 0; i < 16; i++) {
    int jr = i * 4 + ty;
    wt[((size_t)(s * NN + jt * 64 + jr)) * NN + kt * 64 + tx] = f2bf(tl[tx][jr]);
  }
}

// ---- P2[t][s][j][b] = x @ [W1 | W2] + bias, bf16 ----
__global__ __launch_bounds__(256) void precompute(
    const unsigned short* __restrict__ xT, const unsigned short* __restrict__ wt,
    const float* __restrict__ b1, const float* __restrict__ b2,
    unsigned short* __restrict__ P2) {
  int m0 = (blockIdx.x / 24) * 128;
  int n0 = (blockIdx.x % 24) * 128;
  __shared__ unsigned short As[128 * 40];
  __shared__ unsigned short Bs[128 * 40];
  int tid = threadIdx.x;
  int wave = tid >> 6, lane = tid & 63, q = lane >> 4, li = lane & 15;
  int wm = wave >> 1, wn = wave & 1;
  f32x4 acc[4][4];
#pragma unroll
  for (int a = 0; a < 4; a++)
#pragma unroll
    for (int b = 0; b < 4; b++) acc[a][b] = (f32x4)(0.f);

  for (int kk = 0; kk < 32; ++kk) {
    int K0 = kk * 32;
#pragma unroll
    for (int e = 0; e < 2; e++) {
      int c = tid * 2 + e;
      int row = c >> 2, part = c & 3;
      *(u16x8*)&As[row * 40 + part * 8] =
          *(const u16x8*)&xT[(size_t)(m0 + row) * NN + K0 + part * 8];
      *(u16x8*)&Bs[row * 40 + part * 8] =
          *(const u16x8*)&wt[(size_t)(n0 + row) * NN + K0 + part * 8];
    }
    __syncthreads();
    short8 af[4], bfr[4];
#pragma unroll
    for (int mt = 0; mt < 4; mt++)
      af[mt] = *(const short8*)&As[(wm * 64 + mt * 16 + li) * 40 + q * 8];
#pragma unroll
    for (int nt = 0; nt < 4; nt++)
      bfr[nt] = *(const short8*)&Bs[(wn * 64 + nt * 16 + li) * 40 + q * 8];
#pragma unroll
    for (int mt = 0; mt < 4; mt++)
#pragma unroll
      for (int nt = 0; nt < 4; nt++)
        acc[mt][nt] = MFMA16(af[mt], bfr[nt], acc[mt][nt]);
    __syncthreads();
  }
#pragma unroll
  for (int mt = 0; mt < 4; mt++) {
    int m = m0 + wm * 64 + mt * 16 + q * 4;
    int t = m >> 6, b = m & 63;
#pragma unroll
    for (int nt = 0; nt < 4; nt++) {
      int n = n0 + wn * 64 + nt * 16 + li;
      float bias = (n < 2048) ? b1[n] : b2[n - 2048];
      int s = n >> 10, j = n & 1023;
      f32x4 a = acc[mt][nt];
      u16x4 pk;
      pk.x = f2bf(a.x + bias); pk.y = f2bf(a.y + bias);
      pk.z = f2bf(a.z + bias); pk.w = f2bf(a.w + bias);
      *(u16x4*)&P2[(((size_t)t * 3 + s) * NN + j) * 64 + b] = pk;
    }
  }
}

#define AL(p)    __hip_atomic_load((p),  __ATOMIC_RELAXED, __HIP_MEMORY_SCOPE_AGENT)
#define AS(p, v) __hip_atomic_store((p), (v), __ATOMIC_RELAXED, __HIP_MEMORY_SCOPE_AGENT)

// ---- persistent scan, per-writer flag words, agent scope ----
// flags layout: line (mq*4 + w) at word offset (mq*4+w)*64, words 0..15 =
// publish count of producer jt = 16w+i of group mq. One 64B line per
// (group, quarter); lines 256B apart (no false sharing).
// Reader wave w at step t waits: all 16 words of line (mq*4+w) >= t.
// h ring: 4 slots of [64 b][1024 j] bf16; slot t&3 holds h_t.
__global__ __launch_bounds__(256, 1) void gru_scan(
    unsigned short* __restrict__ hb, const unsigned short* __restrict__ wt,
    const unsigned short* __restrict__ P2,
    const float* __restrict__ b1, const float* __restrict__ b2,
    float* __restrict__ out, unsigned* __restrict__ flags) {
  int bid = blockIdx.x;
  int jt = bid & 63, mq = bid >> 6;
  int j0 = jt * 16, m0 = mq * 16;
  int tid = threadIdx.x, wave = tid >> 6, lane = tid & 63, q = lane >> 4, li = lane & 15;
  int kb = wave * 256;   // this wave's K-quarter

  const short8* Bz = (const short8*)&wt[((size_t)(0 * NN + j0 + li)) * NN + kb + q * 8];
  const short8* Br = (const short8*)&wt[((size_t)(1 * NN + j0 + li)) * NN + kb + q * 8];
  const short8* Bv = (const short8*)&wt[((size_t)(2 * NN + j0 + li)) * NN + kb + q * 8];
  short8 wz[8], wr[8], wv[8];
#pragma unroll
  for (int r = 0; r < 8; r++) {
    wz[r] = Bz[r * 4];
    wr[r] = Br[r * 4];
    wv[r] = Bv[r * 4];
  }

  int j = j0 + li;
  int bbase = m0 + q * 4;
  float b1z = b1[j], b1r = b1[NN + j], b2v = b2[j];
  const unsigned short* pz = &P2[((size_t)0 * NN + j) * 64 + bbase];
  const unsigned short* pr = &P2[((size_t)1 * NN + j) * 64 + bbase];
  const unsigned short* pv = &P2[((size_t)2 * NN + j) * 64 + bbase];
  const size_t pstride = (size_t)3 * NN * 64;

  // my flag word (written by lane 0 of wave 0); this wave's 16 poll words
  unsigned* myflag = &flags[(mq * 4 + (jt >> 4)) * 64 + (jt & 15)];
  const unsigned* pollp = &flags[(mq * 4 + wave) * 64 + li];

  // A-fragment offset in u64 units within a ring slot
  const size_t aoff = (size_t)(m0 + li) * 256 + wave * 64 + q * 2;

  f32x4 hc = (f32x4)(0.f);   // wave0: fp32 h tile, resident all 512 steps
  __shared__ f32x4 red[2][9][64];

  for (int t = 0; t < TSTEPS; t++) {
    u16x4 pz4, pr4, pv4;
    if (wave == 0) {   // HBM P2 stream — independent of flags, issue first
      pz4 = *(const u16x4*)pz;
      pr4 = *(const u16x4*)pr;
      pv4 = *(const u16x4*)pv;
    }
    // wait for this quarter's 16 producers to have published h_t
    if (t > 0) {
      unsigned tgt = (unsigned)t;
      int spins = 0;
      while (!__all((int)(AL(pollp) >= tgt))) {
        if (++spins > SPIN_CAP) break;          // hang-proof escape
        if (spins > 64) __builtin_amdgcn_s_sleep(1);  // busy first, back off late
      }
    }
    // coherent A-loads from ring slot t&3: 8x 16B agent-scope (sc1) loads
    // per lane (was 16x 8B) -- halves the per-step LLC transaction burst.
    const unsigned long long* hin =
        (const unsigned long long*)(hb + ((size_t)(t & 3)) * HB_ELEMS) + aoff;
    short8 fa[8];
    asm volatile(
        "global_load_dwordx4 %0, %8, off sc1\n\t"
        "global_load_dwordx4 %1, %8, off offset:64 sc1\n\t"
        "global_load_dwordx4 %2, %8, off offset:128 sc1\n\t"
        "global_load_dwordx4 %3, %8, off offset:192 sc1\n\t"
        "global_load_dwordx4 %4, %8, off offset:256 sc1\n\t"
        "global_load_dwordx4 %5, %8, off offset:320 sc1\n\t"
        "global_load_dwordx4 %6, %8, off offset:384 sc1\n\t"
        "global_load_dwordx4 %7, %8, off offset:448 sc1"
        : "=&v"(fa[0]), "=&v"(fa[1]), "=&v"(fa[2]), "=&v"(fa[3]),
          "=&v"(fa[4]), "=&v"(fa[5]), "=&v"(fa[6]), "=&v"(fa[7])
        : "v"(hin)
        : "memory");
    asm volatile("s_waitcnt vmcnt(0)" ::: "memory");
    __builtin_amdgcn_sched_barrier(0);   // keep MFMAs below the wait

    f32x4 az = (f32x4)(0.f), ar = (f32x4)(0.f), av = (f32x4)(0.f);
#pragma unroll
    for (int r = 0; r < 8; r++) {
      az = MFMA16(fa[r], wz[r], az);
      ar = MFMA16(fa[r], wr[r], ar);
      av = MFMA16(fa[r], wv[r], av);
    }
    // cross-wave K reduction, double-buffered by step parity (race-free)
    f32x4* rp = &red[t & 1][0][0];
    if (wave > 0) {
      rp[((wave - 1) * 3 + 0) * 64 + lane] = az;
      rp[((wave - 1) * 3 + 1) * 64 + lane] = ar;
      rp[((wave - 1) * 3 + 2) * 64 + lane] = av;
    }
    __syncthreads();   // all 4 quarters ready + partials in LDS
    if (wave == 0) {
#pragma unroll
      for (int w = 0; w < 3; w++) {
        az += rp[(w * 3 + 0) * 64 + lane];
        ar += rp[(w * 3 + 1) * 64 + lane];
        av += rp[(w * 3 + 2) * 64 + lane];
      }
#pragma unroll
      for (int reg = 0; reg < 4; reg++) {
        float z = 1.f / (1.f + __expf(-(az[reg] + bf2f(pz4[reg]) + b1z)));
        float r = 1.f / (1.f + __expf(-(ar[reg] + bf2f(pr4[reg]) + b1r)));
        float x = bf2f(pv4[reg]) + r * (av[reg] + b2v);
        float e = __expf(-2.f * fabsf(x));        // overflow-safe tanh
        float th = (1.f - e) / (1.f + e);
        float hh = (x >= 0.f) ? th : -th;
        hc[reg] = z * hc[reg] + (1.f - z) * hh;
      }
      if (t < TSTEPS - 1) {
        // publish h_{t+1} into slot (t+1)&3 (hb[b][j], adjacent-j pairs).
        // Ring-reuse safe: reaching here implies all 64 producers >= t
        // => every block finished step t-1 => step t-3 reads retired.
        unsigned* hout = (unsigned*)(hb + ((size_t)((t + 1) & 3)) * HB_ELEMS);
#pragma unroll
        for (int reg = 0; reg < 4; reg++) {
          unsigned mine = f2bf(hc[reg]);
          unsigned other = (unsigned)__shfl_xor((int)mine, 1, 64);
          if ((lane & 1) == 0) {
            unsigned packed = mine | (other << 16);
            AS(&hout[(size_t)(bbase + reg) * (NN / 2) + (j >> 1)], packed);
          }
        }
        asm volatile("s_waitcnt vmcnt(0)" ::: "memory");  // stores LLC-visible
        if (lane == 0) AS(myflag, (unsigned)(t + 1));     // fire-and-forget
      }
    }
    pz += pstride; pr += pstride; pv += pstride;
  }

  if (wave == 0) {   // out[b*N + j] straight from registers
#pragma unroll
    for (int reg = 0; reg < 4; reg++)
      out[(size_t)(bbase + reg) * NN + j] = hc[reg];
  }
}

extern "C" void kernel_launch(void* const* d_in, const int* in_sizes, int n_in,
                              void* d_out, int out_size, void* d_ws, size_t ws_size,
                              hipStream_t stream) {
  const float* flow_x = (const float*)d_in[0];
  const float* W1 = (const float*)d_in[1];
  const float* b1 = (const float*)d_in[2];
  const float* W2 = (const float*)d_in[3];
  const float* b2 = (const float*)d_in[4];
  float* out = (float*)d_out;
  char* ws = (char*)d_ws;
  size_t off = 0;
  auto take = [&](size_t bytes) -> char* {
    char* p = ws + off;
    off += (bytes + 255) & ~(size_t)255;
    return p;
  };
  unsigned short* wt    = (unsigned short*)take((size_t)3 * 1024 * 1024 * 2);
  unsigned short* xT    = (unsigned short*)take((size_t)32768 * 1024 * 2);
  unsigned short* P2    = (unsigned short*)take((size_t)512 * 3 * 1024 * 64 * 2);
  unsigned short* hb    = (unsigned short*)take((size_t)4 * HB_ELEMS * 2);
  unsigned*       flags = (unsigned*)take((size_t)16 * 64 * 4);

  if (off > ws_size) {
    hipMemsetAsync(d_out, 0, (size_t)out_size * 4, stream);
    return;
  }

  hipMemsetAsync(hb, 0, HB_ELEMS * 2, stream);          // slot 0: h_0 = 0
  hipMemsetAsync(flags, 0, (size_t)16 * 64 * 4, stream);

  prep_w<<<768, 256, 0, stream>>>(W1, W2, wt);
  trans_x<<<8192, 256, 0, stream>>>(flow_x, xT);
  precompute<<<6144, 256, 0, stream>>>(xT, wt, b1, b2, P2);

  void* args[] = {&hb, &wt, &P2, &b1, &b2, &out, &flags};
  hipLaunchCooperativeKernel((const void*)gru_scan, dim3(256), dim3(256),
                             args, 0, stream);
}